// Round 1
// baseline (325.863 us; speedup 1.0000x reference)
//
#include <hip/hip_runtime.h>
#include <cmath>

#define B_N 8192
#define D_N 1024
#define K_N 128

// ---------------- workspace layout (bytes) ----------------
// xnorm2  double[8192]   @ 0        (65536)
// cnorm2  double[128]    @ 65536    (1024)
// dpidx   int[8192]      @ 66560    (32768)
// secidx  int[8192]      @ 99328    (32768)
// maxcos  double[8192]   @ 132096   (65536)
// ct      float[1024*128]@ 197632   (524288)   centroid transposed [d][k]
// psum    double[nch*128*1024] @ 721920
// pcnt    int[nch*128]   @ 721920 + nch*1048576

struct Ent { double v1, v2; int i1, i2; };

// ---- transpose centroid: ct[d][k] = c[k][d] ----
__global__ __launch_bounds__(256) void transpose_cent_k(const float* __restrict__ c,
                                                        float* __restrict__ ct) {
  int e = blockIdx.x * 256 + threadIdx.x;           // < 131072
  int k = e >> 10, d = e & 1023;
  ct[d * K_N + k] = c[e];
}

// ---- row sum-of-squares in f64, one wave per row ----
__global__ __launch_bounds__(256) void norms_k(const float* __restrict__ src,
                                               double* __restrict__ out) {
  int w = threadIdx.x >> 6, lane = threadIdx.x & 63;
  int row = blockIdx.x * 4 + w;
  const float4* s4 = (const float4*)(src + (size_t)row * D_N);
  double acc = 0.0;
#pragma unroll
  for (int e = 0; e < 4; ++e) {
    float4 v = s4[e * 64 + lane];
    acc += (double)v.x * v.x + (double)v.y * v.y + (double)v.z * v.z + (double)v.w * v.w;
  }
#pragma unroll
  for (int off = 32; off; off >>= 1) acc += __shfl_xor(acc, off, 64);
  if (lane == 0) out[row] = acc;
}

// ---- assign: cos-sim GEMM (32 rows x 128 cents), argmax + top2 + maxcos ----
__global__ __launch_bounds__(256) void assign_k(const float* __restrict__ dp,
                                                const float* __restrict__ ct,
                                                const double* __restrict__ xnorm2,
                                                const double* __restrict__ cnorm2,
                                                int* __restrict__ dpidx,
                                                int* __restrict__ secidx,
                                                double* __restrict__ maxcos) {
  __shared__ __align__(16) float xs[32 * 64];      // [row][d] linear
  __shared__ __align__(16) float cs[64 * K_N];     // [d][k]  linear (32 KB, reused for merge)
  const int tid = threadIdx.x;
  const int rg = tid >> 5;          // 0..7  -> rows rg*4..rg*4+3
  const int cg = tid & 31;          // 0..31 -> cents cg*4..cg*4+3
  const int rowbase = blockIdx.x * 32;

  float a32[4][4];
  double a64[4][4];
#pragma unroll
  for (int r = 0; r < 4; ++r)
#pragma unroll
    for (int q = 0; q < 4; ++q) a64[r][q] = 0.0;

  for (int ch = 0; ch < 16; ++ch) {
    const int db = ch * 64;
    // stage x tile: 32 rows x 64 d
#pragma unroll
    for (int i = 0; i < 2; ++i) {
      int fid = tid + i * 256;
      int r = fid >> 4, c4 = (fid & 15) * 4;
      *(float4*)&xs[r * 64 + c4] =
          *(const float4*)&dp[(size_t)(rowbase + r) * D_N + db + c4];
    }
    // stage ct chunk: rows db..db+63 of ct (each K_N wide), coalesced
#pragma unroll
    for (int i = 0; i < 8; ++i) {
      int fid = tid + i * 256;
      int dd = fid >> 5, kq = (fid & 31) * 4;
      *(float4*)&cs[dd * K_N + kq] =
          *(const float4*)&ct[(size_t)(db + dd) * K_N + kq];
    }
    __syncthreads();

#pragma unroll
    for (int r = 0; r < 4; ++r)
#pragma unroll
      for (int q = 0; q < 4; ++q) a32[r][q] = 0.0f;

#pragma unroll 2
    for (int dd = 0; dd < 64; dd += 4) {
      float4 cf[4];
#pragma unroll
      for (int e = 0; e < 4; ++e)
        cf[e] = *(const float4*)&cs[(dd + e) * K_N + cg * 4];
#pragma unroll
      for (int r = 0; r < 4; ++r) {
        float4 xv = *(const float4*)&xs[(rg * 4 + r) * 64 + dd];
        a32[r][0] += xv.x * cf[0].x + xv.y * cf[1].x + xv.z * cf[2].x + xv.w * cf[3].x;
        a32[r][1] += xv.x * cf[0].y + xv.y * cf[1].y + xv.z * cf[2].y + xv.w * cf[3].y;
        a32[r][2] += xv.x * cf[0].z + xv.y * cf[1].z + xv.z * cf[2].z + xv.w * cf[3].z;
        a32[r][3] += xv.x * cf[0].w + xv.y * cf[1].w + xv.z * cf[2].w + xv.w * cf[3].w;
      }
    }
#pragma unroll
    for (int r = 0; r < 4; ++r)
#pragma unroll
      for (int q = 0; q < 4; ++q) a64[r][q] += (double)a32[r][q];
    __syncthreads();
  }

  // epilogue: cos = dot / (||x|| * ||c||), local top2 then block merge
  double xinv[4], cinv[4];
#pragma unroll
  for (int r = 0; r < 4; ++r) {
    double n = sqrt(xnorm2[rowbase + rg * 4 + r]);
    xinv[r] = 1.0 / fmax(n, 1e-8);
  }
#pragma unroll
  for (int q = 0; q < 4; ++q) {
    double n = sqrt(cnorm2[cg * 4 + q]);
    cinv[q] = 1.0 / fmax(n, 1e-8);
  }

  Ent* mb = (Ent*)cs;   // 32 rows x 32 groups x 24B = 24 KB, fits in cs
#pragma unroll
  for (int r = 0; r < 4; ++r) {
    double b1 = -1e300, b2 = -1e300; int i1 = 0, i2 = 0;
#pragma unroll
    for (int q = 0; q < 4; ++q) {
      double v = a64[r][q] * xinv[r] * cinv[q];
      int c = cg * 4 + q;
      if (v > b1) { b2 = b1; i2 = i1; b1 = v; i1 = c; }
      else if (v > b2) { b2 = v; i2 = c; }
    }
    Ent& e = mb[(rg * 4 + r) * 32 + cg];
    e.v1 = b1; e.v2 = b2; e.i1 = i1; e.i2 = i2;
  }
  __syncthreads();
  if (tid < 32) {
    int row = tid;
    double b1 = -1e300, b2 = -1e300; int i1 = 0, i2 = 0;
    for (int g = 0; g < 32; ++g) {   // ascending centroid-index order -> stable ties
      Ent e = mb[row * 32 + g];
      if (e.v1 > b1) { b2 = b1; i2 = i1; b1 = e.v1; i1 = e.i1; }
      else if (e.v1 > b2) { b2 = e.v1; i2 = e.i1; }
      if (e.v2 > b2) { b2 = e.v2; i2 = e.i2; }
    }
    dpidx[rowbase + row] = i1;
    secidx[rowbase + row] = i2;
    maxcos[rowbase + row] = b1;
  }
}

// ---- gather dp_centroid & hard_negative ----
__global__ __launch_bounds__(256) void gather_k(const float* __restrict__ cent,
                                                const int* __restrict__ dpidx,
                                                const int* __restrict__ secidx,
                                                float* __restrict__ out0,
                                                float* __restrict__ out2) {
  int row = blockIdx.x, t = threadIdx.x;
  int i1 = dpidx[row], i2 = secidx[row];
  float4 v1 = *(const float4*)&cent[(size_t)i1 * D_N + t * 4];
  float4 v2 = *(const float4*)&cent[(size_t)i2 * D_N + t * 4];
  *(float4*)&out0[(size_t)row * D_N + t * 4] = v1;
  *(float4*)&out2[(size_t)row * D_N + t * 4] = v2;
}

// ---- dp_cluster + cos_mask (dominant kernel) ----
__global__ __launch_bounds__(256) void mask_k(const float* __restrict__ batch,
                                              const int* __restrict__ dpidx,
                                              const double* __restrict__ maxcos,
                                              float* __restrict__ out1,
                                              float* __restrict__ out3) {
  const int i = blockIdx.x;
  const int ci = dpidx[i];
  const double thr = maxcos[i];
  const size_t rb = (size_t)i * B_N;
#pragma unroll 2
  for (int it = 0; it < 8; ++it) {
    int j = it * 1024 + threadIdx.x * 4;
    int4 c4 = *(const int4*)&dpidx[j];
    int m0 = (c4.x == ci) & ((j + 0) != i);
    int m1 = (c4.y == ci) & ((j + 1) != i);
    int m2 = (c4.z == ci) & ((j + 2) != i);
    int m3 = (c4.w == ci) & ((j + 3) != i);
    float4 bv = make_float4(0.f, 0.f, 0.f, 0.f);
    if (m0 | m1 | m2 | m3)                       // exec-masked: skip untouched lines
      bv = *(const float4*)&batch[rb + j];
    float4 cl = make_float4((float)m0, (float)m1, (float)m2, (float)m3);
    float4 mk = make_float4(
        (m0 && ((double)bv.x > thr)) ? -10000.f : 0.f,
        (m1 && ((double)bv.y > thr)) ? -10000.f : 0.f,
        (m2 && ((double)bv.z > thr)) ? -10000.f : 0.f,
        (m3 && ((double)bv.w > thr)) ? -10000.f : 0.f);
    *(float4*)&out1[rb + j] = cl;
    *(float4*)&out3[rb + j] = mk;
  }
}

// ---- deterministic per-(cluster, row-chunk) partial sums ----
__global__ __launch_bounds__(256) void cluster_partial_k(const float* __restrict__ dp,
                                                         const int* __restrict__ dpidx,
                                                         double* __restrict__ psum,
                                                         int* __restrict__ pcnt,
                                                         int nch) {
  const int k = blockIdx.x & 127;
  const int ch = blockIdx.x >> 7;
  const int rows = B_N / nch;
  const int r0 = ch * rows;
  const int t = threadIdx.x;
  double a0 = 0, a1 = 0, a2 = 0, a3 = 0;
  int cnt = 0;
  for (int r = r0; r < r0 + rows; r += 4) {
    int4 q = *(const int4*)&dpidx[r];
    if (q.x == k) { float4 v = *(const float4*)&dp[(size_t)(r + 0) * D_N + t * 4];
                    a0 += v.x; a1 += v.y; a2 += v.z; a3 += v.w; ++cnt; }
    if (q.y == k) { float4 v = *(const float4*)&dp[(size_t)(r + 1) * D_N + t * 4];
                    a0 += v.x; a1 += v.y; a2 += v.z; a3 += v.w; ++cnt; }
    if (q.z == k) { float4 v = *(const float4*)&dp[(size_t)(r + 2) * D_N + t * 4];
                    a0 += v.x; a1 += v.y; a2 += v.z; a3 += v.w; ++cnt; }
    if (q.w == k) { float4 v = *(const float4*)&dp[(size_t)(r + 3) * D_N + t * 4];
                    a0 += v.x; a1 += v.y; a2 += v.z; a3 += v.w; ++cnt; }
  }
  double* o = psum + ((size_t)(ch * 128 + k)) * D_N + t * 4;
  o[0] = a0; o[1] = a1; o[2] = a2; o[3] = a3;
  if (t == 0) pcnt[ch * 128 + k] = cnt;
}

// ---- new_centroid = cnt>0 ? 0.5*sum + 0.5*c : c ----
__global__ __launch_bounds__(256) void finalize_k(const float* __restrict__ cent,
                                                  const double* __restrict__ psum,
                                                  const int* __restrict__ pcnt,
                                                  float* __restrict__ out4,
                                                  int nch) {
  int e = blockIdx.x * 256 + threadIdx.x;   // < 131072
  int k = e >> 10;
  int cnt = 0;
  double s = 0.0;
  for (int ch = 0; ch < nch; ++ch) {
    cnt += pcnt[ch * 128 + k];
    s += psum[(size_t)(ch * 128 + k) * D_N + (e & 1023)];
  }
  float c = cent[e];
  out4[e] = (cnt > 0) ? (float)(0.5 * s + 0.5 * (double)c) : c;
}

extern "C" void kernel_launch(void* const* d_in, const int* in_sizes, int n_in,
                              void* d_out, int out_size, void* d_ws, size_t ws_size,
                              hipStream_t stream) {
  const float* dp    = (const float*)d_in[0];   // 8192 x 1024
  const float* cent  = (const float*)d_in[1];   // 128 x 1024
  const float* batch = (const float*)d_in[2];   // 8192 x 8192

  float* out  = (float*)d_out;
  float* out0 = out;                 // dp_centroid   8192x1024
  float* out1 = out0 + 8388608;      // dp_cluster    8192x8192
  float* out2 = out1 + 67108864;     // hard_negative 8192x1024
  float* out3 = out2 + 8388608;      // cos_mask      8192x8192
  float* out4 = out3 + 67108864;     // new_centroid  128x1024

  char* w = (char*)d_ws;
  double* xnorm2 = (double*)(w + 0);
  double* cnorm2 = (double*)(w + 65536);
  int*    dpidx  = (int*)(w + 66560);
  int*    secidx = (int*)(w + 99328);
  double* maxcos = (double*)(w + 132096);
  float*  ct     = (float*)(w + 197632);
  const size_t psum_base = 721920;

  int nch = 4;
  while (nch > 1 &&
         psum_base + (size_t)nch * (128ull * 1024 * 8 + 128 * 4) > ws_size)
    nch >>= 1;
  double* psum = (double*)(w + psum_base);
  int*    pcnt = (int*)(w + psum_base + (size_t)nch * 128 * 1024 * 8);

  transpose_cent_k<<<dim3(512), dim3(256), 0, stream>>>(cent, ct);
  norms_k<<<dim3(2048), dim3(256), 0, stream>>>(dp, xnorm2);
  norms_k<<<dim3(32), dim3(256), 0, stream>>>(cent, cnorm2);
  assign_k<<<dim3(256), dim3(256), 0, stream>>>(dp, ct, xnorm2, cnorm2,
                                                dpidx, secidx, maxcos);
  gather_k<<<dim3(8192), dim3(256), 0, stream>>>(cent, dpidx, secidx, out0, out2);
  mask_k<<<dim3(8192), dim3(256), 0, stream>>>(batch, dpidx, maxcos, out1, out3);
  cluster_partial_k<<<dim3(128 * nch), dim3(256), 0, stream>>>(dp, dpidx, psum, pcnt, nch);
  finalize_k<<<dim3(512), dim3(256), 0, stream>>>(cent, psum, pcnt, out4, nch);
}

// Round 2
// 270.042 us; speedup vs baseline: 1.2067x; 1.2067x over previous
//
#include <hip/hip_runtime.h>
#include <cmath>

#define B_N 8192
#define D_N 1024
#define K_N 128

// ---------------- workspace layout (bytes) ----------------
// xnorm2  double[8192]      @ 0         (65536)
// cnorm2  double[128]       @ 65536     (1024)
// dpidx   int[8192]         @ 66560     (32768)
// maxcos  double[8192]      @ 99328     (65536)
// ct      float[1024*128]   @ 164864    (524288)   centroid transposed [d][k]
// pdot    double[2*8192*128]@ 689152    (16777216) split-D partial dots
// psum    double[nch*128*1024] @ 17466368
// pcnt    int[nch*128]      @ after psum

// ---- transpose centroid: ct[d][k] = c[k][d] ----
__global__ __launch_bounds__(256) void transpose_cent_k(const float* __restrict__ c,
                                                        float* __restrict__ ct) {
  int e = blockIdx.x * 256 + threadIdx.x;           // < 131072
  int k = e >> 10, d = e & 1023;
  ct[d * K_N + k] = c[e];
}

// ---- row sum-of-squares in f64, one wave per row ----
__global__ __launch_bounds__(256) void norms_k(const float* __restrict__ src,
                                               double* __restrict__ out) {
  int w = threadIdx.x >> 6, lane = threadIdx.x & 63;
  int row = blockIdx.x * 4 + w;
  const float4* s4 = (const float4*)(src + (size_t)row * D_N);
  double acc = 0.0;
#pragma unroll
  for (int e = 0; e < 4; ++e) {
    float4 v = s4[e * 64 + lane];
    acc += (double)v.x * v.x + (double)v.y * v.y + (double)v.z * v.z + (double)v.w * v.w;
  }
#pragma unroll
  for (int off = 32; off; off >>= 1) acc += __shfl_xor(acc, off, 64);
  if (lane == 0) out[row] = acc;
}

// ---- stage 1: split-D dot-product GEMM, f64 partial dots to ws ----
// grid 512: block = (h = blockIdx>>8 in {0,1}, rb = blockIdx&255)
// block computes rows rb*32..+32 x all 128 cents over D half h.
__global__ __launch_bounds__(256) void assign_part_k(const float* __restrict__ dp,
                                                     const float* __restrict__ ct,
                                                     double* __restrict__ pdot) {
  __shared__ __align__(16) float xs[32 * 64];      // [row][d]
  __shared__ __align__(16) float cs[64 * K_N];     // [d][k]
  const int tid = threadIdx.x;
  const int rg = tid >> 5;          // 0..7  -> rows rg*4..+4
  const int cg = tid & 31;          // 0..31 -> cents cg*4..+4
  const int h = blockIdx.x >> 8;
  const int rowbase = (blockIdx.x & 255) * 32;
  const int dbase = h * 512;

  float a32[4][4];
  double a64[4][4];
#pragma unroll
  for (int r = 0; r < 4; ++r)
#pragma unroll
    for (int q = 0; q < 4; ++q) a64[r][q] = 0.0;

  for (int ch = 0; ch < 8; ++ch) {
    const int db = dbase + ch * 64;
#pragma unroll
    for (int i = 0; i < 2; ++i) {
      int fid = tid + i * 256;
      int r = fid >> 4, c4 = (fid & 15) * 4;
      *(float4*)&xs[r * 64 + c4] =
          *(const float4*)&dp[(size_t)(rowbase + r) * D_N + db + c4];
    }
#pragma unroll
    for (int i = 0; i < 8; ++i) {
      int fid = tid + i * 256;
      int dd = fid >> 5, kq = (fid & 31) * 4;
      *(float4*)&cs[dd * K_N + kq] =
          *(const float4*)&ct[(size_t)(db + dd) * K_N + kq];
    }
    __syncthreads();

#pragma unroll
    for (int r = 0; r < 4; ++r)
#pragma unroll
      for (int q = 0; q < 4; ++q) a32[r][q] = 0.0f;

#pragma unroll 2
    for (int dd = 0; dd < 64; dd += 4) {
      float4 cf[4];
#pragma unroll
      for (int e = 0; e < 4; ++e)
        cf[e] = *(const float4*)&cs[(dd + e) * K_N + cg * 4];
#pragma unroll
      for (int r = 0; r < 4; ++r) {
        float4 xv = *(const float4*)&xs[(rg * 4 + r) * 64 + dd];
        a32[r][0] += xv.x * cf[0].x + xv.y * cf[1].x + xv.z * cf[2].x + xv.w * cf[3].x;
        a32[r][1] += xv.x * cf[0].y + xv.y * cf[1].y + xv.z * cf[2].y + xv.w * cf[3].y;
        a32[r][2] += xv.x * cf[0].z + xv.y * cf[1].z + xv.z * cf[2].z + xv.w * cf[3].z;
        a32[r][3] += xv.x * cf[0].w + xv.y * cf[1].w + xv.z * cf[2].w + xv.w * cf[3].w;
      }
    }
#pragma unroll
    for (int r = 0; r < 4; ++r)
#pragma unroll
      for (int q = 0; q < 4; ++q) a64[r][q] += (double)a32[r][q];
    __syncthreads();
  }

  double* base = pdot + (size_t)h * B_N * K_N;
#pragma unroll
  for (int r = 0; r < 4; ++r) {
    int row = rowbase + rg * 4 + r;
    double* o = base + (size_t)row * K_N + cg * 4;
    *(double2*)(o)     = make_double2(a64[r][0], a64[r][1]);
    *(double2*)(o + 2) = make_double2(a64[r][2], a64[r][3]);
  }
}

// ---- stage 2: per-row top-2 (f64, index-stable) + fused gather ----
// one wave per row; grid 2048 x 256
__global__ __launch_bounds__(256) void top2_gather_k(const double* __restrict__ pdot,
                                                     const double* __restrict__ xnorm2,
                                                     const double* __restrict__ cnorm2,
                                                     const float* __restrict__ cent,
                                                     int* __restrict__ dpidx,
                                                     double* __restrict__ maxcos,
                                                     float* __restrict__ out0,
                                                     float* __restrict__ out2) {
  const int w = threadIdx.x >> 6, l = threadIdx.x & 63;
  const int row = blockIdx.x * 4 + w;
  const double* p0 = pdot + (size_t)row * K_N;
  const double* p1 = pdot + (size_t)B_N * K_N + (size_t)row * K_N;
  double2 a = *(const double2*)&p0[2 * l];
  double2 b = *(const double2*)&p1[2 * l];
  double xinv = 1.0 / fmax(sqrt(xnorm2[row]), 1e-8);
  double2 cn = *(const double2*)&cnorm2[2 * l];
  double c0 = (a.x + b.x) * xinv / fmax(sqrt(cn.x), 1e-8);
  double c1 = (a.y + b.y) * xinv / fmax(sqrt(cn.y), 1e-8);

  double v1, v2; int i1, i2;
  if (c0 >= c1) { v1 = c0; i1 = 2 * l;     v2 = c1; i2 = 2 * l + 1; }
  else          { v1 = c1; i1 = 2 * l + 1; v2 = c0; i2 = 2 * l; }

#pragma unroll
  for (int off = 1; off < 64; off <<= 1) {
    double pv1 = __shfl_xor(v1, off, 64), pv2 = __shfl_xor(v2, off, 64);
    int    pi1 = __shfl_xor(i1, off, 64), pi2 = __shfl_xor(i2, off, 64);
    bool pb = (pv1 > v1) || (pv1 == v1 && pi1 < i1);
    double w1v = pb ? pv1 : v1;  int w1i = pb ? pi1 : i1;
    double lv  = pb ? v1  : pv1; int li  = pb ? i1  : pi1;   // loser of firsts
    double sv  = pb ? pv2 : v2;  int si  = pb ? pi2 : i2;    // winner-side second
    bool lb = (lv > sv) || (lv == sv && li < si);
    v1 = w1v; i1 = w1i;
    v2 = lb ? lv : sv; i2 = lb ? li : si;
  }
  if (l == 0) { dpidx[row] = i1; maxcos[row] = v1; }

  // fused gather: dp_centroid (out0) and hard_negative (out2)
  const float4* g1 = (const float4*)(cent + (size_t)i1 * D_N);
  const float4* g2 = (const float4*)(cent + (size_t)i2 * D_N);
  float4* o0 = (float4*)(out0 + (size_t)row * D_N);
  float4* o2 = (float4*)(out2 + (size_t)row * D_N);
#pragma unroll
  for (int e = 0; e < 4; ++e) {
    o0[e * 64 + l] = g1[e * 64 + l];
    o2[e * 64 + l] = g2[e * 64 + l];
  }
}

// ---- dp_cluster + cos_mask (dominant, write-bound) ----
__global__ __launch_bounds__(256) void mask_k(const float* __restrict__ batch,
                                              const int* __restrict__ dpidx,
                                              const double* __restrict__ maxcos,
                                              float* __restrict__ out1,
                                              float* __restrict__ out3) {
  const int i = blockIdx.x;
  const int ci = dpidx[i];
  const double thr = maxcos[i];
  const size_t rb = (size_t)i * B_N;
#pragma unroll 2
  for (int it = 0; it < 8; ++it) {
    int j = it * 1024 + threadIdx.x * 4;
    int4 c4 = *(const int4*)&dpidx[j];
    int m0 = (c4.x == ci) & ((j + 0) != i);
    int m1 = (c4.y == ci) & ((j + 1) != i);
    int m2 = (c4.z == ci) & ((j + 2) != i);
    int m3 = (c4.w == ci) & ((j + 3) != i);
    float4 bv = make_float4(0.f, 0.f, 0.f, 0.f);
    if (m0 | m1 | m2 | m3)                       // exec-masked sparse fetch
      bv = *(const float4*)&batch[rb + j];
    float4 cl = make_float4((float)m0, (float)m1, (float)m2, (float)m3);
    float4 mk = make_float4(
        (m0 && ((double)bv.x > thr)) ? -10000.f : 0.f,
        (m1 && ((double)bv.y > thr)) ? -10000.f : 0.f,
        (m2 && ((double)bv.z > thr)) ? -10000.f : 0.f,
        (m3 && ((double)bv.w > thr)) ? -10000.f : 0.f);
    *(float4*)&out1[rb + j] = cl;
    *(float4*)&out3[rb + j] = mk;
  }
}

// ---- deterministic per-(cluster, row-chunk) partial sums ----
__global__ __launch_bounds__(256) void cluster_partial_k(const float* __restrict__ dp,
                                                         const int* __restrict__ dpidx,
                                                         double* __restrict__ psum,
                                                         int* __restrict__ pcnt,
                                                         int nch) {
  const int k = blockIdx.x & 127;
  const int ch = blockIdx.x >> 7;
  const int rows = B_N / nch;
  const int r0 = ch * rows;
  const int t = threadIdx.x;
  double a0 = 0, a1 = 0, a2 = 0, a3 = 0;
  int cnt = 0;
  for (int r = r0; r < r0 + rows; r += 4) {
    int4 q = *(const int4*)&dpidx[r];
    if (q.x == k) { float4 v = *(const float4*)&dp[(size_t)(r + 0) * D_N + t * 4];
                    a0 += v.x; a1 += v.y; a2 += v.z; a3 += v.w; ++cnt; }
    if (q.y == k) { float4 v = *(const float4*)&dp[(size_t)(r + 1) * D_N + t * 4];
                    a0 += v.x; a1 += v.y; a2 += v.z; a3 += v.w; ++cnt; }
    if (q.z == k) { float4 v = *(const float4*)&dp[(size_t)(r + 2) * D_N + t * 4];
                    a0 += v.x; a1 += v.y; a2 += v.z; a3 += v.w; ++cnt; }
    if (q.w == k) { float4 v = *(const float4*)&dp[(size_t)(r + 3) * D_N + t * 4];
                    a0 += v.x; a1 += v.y; a2 += v.z; a3 += v.w; ++cnt; }
  }
  double* o = psum + ((size_t)(ch * 128 + k)) * D_N + t * 4;
  o[0] = a0; o[1] = a1; o[2] = a2; o[3] = a3;
  if (t == 0) pcnt[ch * 128 + k] = cnt;
}

// ---- new_centroid = cnt>0 ? 0.5*sum + 0.5*c : c ----
__global__ __launch_bounds__(256) void finalize_k(const float* __restrict__ cent,
                                                  const double* __restrict__ psum,
                                                  const int* __restrict__ pcnt,
                                                  float* __restrict__ out4,
                                                  int nch) {
  int e = blockIdx.x * 256 + threadIdx.x;   // < 131072
  int k = e >> 10;
  int cnt = 0;
  double s = 0.0;
  for (int ch = 0; ch < nch; ++ch) {
    cnt += pcnt[ch * 128 + k];
    s += psum[(size_t)(ch * 128 + k) * D_N + (e & 1023)];
  }
  float c = cent[e];
  out4[e] = (cnt > 0) ? (float)(0.5 * s + 0.5 * (double)c) : c;
}

extern "C" void kernel_launch(void* const* d_in, const int* in_sizes, int n_in,
                              void* d_out, int out_size, void* d_ws, size_t ws_size,
                              hipStream_t stream) {
  const float* dp    = (const float*)d_in[0];   // 8192 x 1024
  const float* cent  = (const float*)d_in[1];   // 128 x 1024
  const float* batch = (const float*)d_in[2];   // 8192 x 8192

  float* out  = (float*)d_out;
  float* out0 = out;                 // dp_centroid   8192x1024
  float* out1 = out0 + 8388608;      // dp_cluster    8192x8192
  float* out2 = out1 + 67108864;     // hard_negative 8192x1024
  float* out3 = out2 + 8388608;      // cos_mask      8192x8192
  float* out4 = out3 + 67108864;     // new_centroid  128x1024

  char* w = (char*)d_ws;
  double* xnorm2 = (double*)(w + 0);
  double* cnorm2 = (double*)(w + 65536);
  int*    dpidx  = (int*)(w + 66560);
  double* maxcos = (double*)(w + 99328);
  float*  ct     = (float*)(w + 164864);
  double* pdot   = (double*)(w + 689152);
  const size_t psum_base = 689152 + 16777216;   // 17466368

  int nch = 16;
  while (nch > 1 &&
         psum_base + (size_t)nch * (128ull * 1024 * 8 + 128 * 4) > ws_size)
    nch >>= 1;
  double* psum = (double*)(w + psum_base);
  int*    pcnt = (int*)(w + psum_base + (size_t)nch * 128 * 1024 * 8);

  transpose_cent_k<<<dim3(512), dim3(256), 0, stream>>>(cent, ct);
  norms_k<<<dim3(2048), dim3(256), 0, stream>>>(dp, xnorm2);
  norms_k<<<dim3(32), dim3(256), 0, stream>>>(cent, cnorm2);
  assign_part_k<<<dim3(512), dim3(256), 0, stream>>>(dp, ct, pdot);
  top2_gather_k<<<dim3(2048), dim3(256), 0, stream>>>(pdot, xnorm2, cnorm2, cent,
                                                      dpidx, maxcos, out0, out2);
  mask_k<<<dim3(8192), dim3(256), 0, stream>>>(batch, dpidx, maxcos, out1, out3);
  cluster_partial_k<<<dim3(128 * nch), dim3(256), 0, stream>>>(dp, dpidx, psum, pcnt, nch);
  finalize_k<<<dim3(512), dim3(256), 0, stream>>>(cent, psum, pcnt, out4, nch);
}

// Round 3
// 261.784 us; speedup vs baseline: 1.2448x; 1.0315x over previous
//
#include <hip/hip_runtime.h>
#include <cmath>

#define B_N 8192
#define D_N 1024
#define K_N 128

// ---------------- workspace layout (bytes) ----------------
// xnorm2  double[8192]      @ 0         (65536)
// cnorm2  double[128]       @ 65536     (1024)
// dpidx   int[8192]         @ 66560     (32768)
// maxcos  double[8192]      @ 99328     (65536)
// ct      float[1024*128]   @ 164864    (524288)   centroid transposed [d][k]
// pdot    float[4*8192*128] @ 689152    (16777216) split-D(4) f32 partial dots
// psum    double[nch*128*1024] @ 17466368
// pcnt    int[nch*128]      @ after psum

// ---- transpose centroid: ct[d][k] = c[k][d] ----
__global__ __launch_bounds__(256) void transpose_cent_k(const float* __restrict__ c,
                                                        float* __restrict__ ct) {
  int e = blockIdx.x * 256 + threadIdx.x;           // < 131072
  int k = e >> 10, d = e & 1023;
  ct[d * K_N + k] = c[e];
}

// ---- row sum-of-squares in f64, one wave per row ----
__global__ __launch_bounds__(256) void norms_k(const float* __restrict__ src,
                                               double* __restrict__ out) {
  int w = threadIdx.x >> 6, lane = threadIdx.x & 63;
  int row = blockIdx.x * 4 + w;
  const float4* s4 = (const float4*)(src + (size_t)row * D_N);
  double acc = 0.0;
#pragma unroll
  for (int e = 0; e < 4; ++e) {
    float4 v = s4[e * 64 + lane];
    acc += (double)v.x * v.x + (double)v.y * v.y + (double)v.z * v.z + (double)v.w * v.w;
  }
#pragma unroll
  for (int off = 32; off; off >>= 1) acc += __shfl_xor(acc, off, 64);
  if (lane == 0) out[row] = acc;
}

// ---- stage 1: split-D(4) dot-product GEMM, f32 partial dots to ws ----
// grid 1024: h = blockIdx>>8 in {0..3}, rb = blockIdx&255
// block computes rows rb*32..+32 x all 128 cents over D quarter h.
// 40 KB LDS -> 4 blocks/CU = 4 waves/SIMD (latency hiding across blocks).
__global__ __launch_bounds__(256, 4) void assign_part_k(const float* __restrict__ dp,
                                                        const float* __restrict__ ct,
                                                        float* __restrict__ pdot) {
  __shared__ __align__(16) float xs[32 * 64];      // [row][d]   8 KB
  __shared__ __align__(16) float cs[64 * K_N];     // [d][k]    32 KB
  const int tid = threadIdx.x;
  const int rg = tid >> 5;          // 0..7  -> rows rg*4..+4
  const int cg = tid & 31;          // 0..31 -> cents cg*4..+4
  const int h = blockIdx.x >> 8;
  const int rowbase = (blockIdx.x & 255) * 32;
  const int dbase = h * 256;

  float a32[4][4];
  double a64[4][4];
#pragma unroll
  for (int r = 0; r < 4; ++r)
#pragma unroll
    for (int q = 0; q < 4; ++q) a64[r][q] = 0.0;

  for (int ch = 0; ch < 4; ++ch) {
    const int db = dbase + ch * 64;
#pragma unroll
    for (int i = 0; i < 2; ++i) {
      int fid = tid + i * 256;
      int r = fid >> 4, c4 = (fid & 15) * 4;
      *(float4*)&xs[r * 64 + c4] =
          *(const float4*)&dp[(size_t)(rowbase + r) * D_N + db + c4];
    }
#pragma unroll
    for (int i = 0; i < 8; ++i) {
      int fid = tid + i * 256;
      int dd = fid >> 5, kq = (fid & 31) * 4;
      *(float4*)&cs[dd * K_N + kq] =
          *(const float4*)&ct[(size_t)(db + dd) * K_N + kq];
    }
    __syncthreads();

#pragma unroll
    for (int r = 0; r < 4; ++r)
#pragma unroll
      for (int q = 0; q < 4; ++q) a32[r][q] = 0.0f;

#pragma unroll 2
    for (int dd = 0; dd < 64; dd += 4) {
      float4 cf[4];
#pragma unroll
      for (int e = 0; e < 4; ++e)
        cf[e] = *(const float4*)&cs[(dd + e) * K_N + cg * 4];
#pragma unroll
      for (int r = 0; r < 4; ++r) {
        float4 xv = *(const float4*)&xs[(rg * 4 + r) * 64 + dd];
        a32[r][0] += xv.x * cf[0].x + xv.y * cf[1].x + xv.z * cf[2].x + xv.w * cf[3].x;
        a32[r][1] += xv.x * cf[0].y + xv.y * cf[1].y + xv.z * cf[2].y + xv.w * cf[3].y;
        a32[r][2] += xv.x * cf[0].z + xv.y * cf[1].z + xv.z * cf[2].z + xv.w * cf[3].z;
        a32[r][3] += xv.x * cf[0].w + xv.y * cf[1].w + xv.z * cf[2].w + xv.w * cf[3].w;
      }
    }
#pragma unroll
    for (int r = 0; r < 4; ++r)
#pragma unroll
      for (int q = 0; q < 4; ++q) a64[r][q] += (double)a32[r][q];
    __syncthreads();
  }

  float* base = pdot + (size_t)h * B_N * K_N;
#pragma unroll
  for (int r = 0; r < 4; ++r) {
    int row = rowbase + rg * 4 + r;
    float* o = base + (size_t)row * K_N + cg * 4;
    float4 v = make_float4((float)a64[r][0], (float)a64[r][1],
                           (float)a64[r][2], (float)a64[r][3]);
    *(float4*)o = v;
  }
}

// ---- stage 2: per-row top-2 (f64, index-stable) + fused gather ----
// one wave per row; grid 2048 x 256
__global__ __launch_bounds__(256) void top2_gather_k(const float* __restrict__ pdot,
                                                     const double* __restrict__ xnorm2,
                                                     const double* __restrict__ cnorm2,
                                                     const float* __restrict__ cent,
                                                     int* __restrict__ dpidx,
                                                     double* __restrict__ maxcos,
                                                     float* __restrict__ out0,
                                                     float* __restrict__ out2) {
  const int w = threadIdx.x >> 6, l = threadIdx.x & 63;
  const int row = blockIdx.x * 4 + w;
  double s0 = 0.0, s1 = 0.0;
#pragma unroll
  for (int h = 0; h < 4; ++h) {
    float2 p = *(const float2*)&pdot[(size_t)h * B_N * K_N + (size_t)row * K_N + 2 * l];
    s0 += (double)p.x; s1 += (double)p.y;
  }
  double xinv = 1.0 / fmax(sqrt(xnorm2[row]), 1e-8);
  double2 cn = *(const double2*)&cnorm2[2 * l];
  double c0 = s0 * xinv / fmax(sqrt(cn.x), 1e-8);
  double c1 = s1 * xinv / fmax(sqrt(cn.y), 1e-8);

  double v1, v2; int i1, i2;
  if (c0 >= c1) { v1 = c0; i1 = 2 * l;     v2 = c1; i2 = 2 * l + 1; }
  else          { v1 = c1; i1 = 2 * l + 1; v2 = c0; i2 = 2 * l; }

#pragma unroll
  for (int off = 1; off < 64; off <<= 1) {
    double pv1 = __shfl_xor(v1, off, 64), pv2 = __shfl_xor(v2, off, 64);
    int    pi1 = __shfl_xor(i1, off, 64), pi2 = __shfl_xor(i2, off, 64);
    bool pb = (pv1 > v1) || (pv1 == v1 && pi1 < i1);
    double w1v = pb ? pv1 : v1;  int w1i = pb ? pi1 : i1;
    double lv  = pb ? v1  : pv1; int li  = pb ? i1  : pi1;   // loser of firsts
    double sv  = pb ? pv2 : v2;  int si  = pb ? pi2 : i2;    // winner-side second
    bool lb = (lv > sv) || (lv == sv && li < si);
    v1 = w1v; i1 = w1i;
    v2 = lb ? lv : sv; i2 = lb ? li : si;
  }
  if (l == 0) { dpidx[row] = i1; maxcos[row] = v1; }

  // fused gather: dp_centroid (out0) and hard_negative (out2)
  const float4* g1 = (const float4*)(cent + (size_t)i1 * D_N);
  const float4* g2 = (const float4*)(cent + (size_t)i2 * D_N);
  float4* o0 = (float4*)(out0 + (size_t)row * D_N);
  float4* o2 = (float4*)(out2 + (size_t)row * D_N);
#pragma unroll
  for (int e = 0; e < 4; ++e) {
    o0[e * 64 + l] = g1[e * 64 + l];
    o2[e * 64 + l] = g2[e * 64 + l];
  }
}

// ---- dp_cluster + cos_mask (dominant, write-bound) ----
__global__ __launch_bounds__(256) void mask_k(const float* __restrict__ batch,
                                              const int* __restrict__ dpidx,
                                              const double* __restrict__ maxcos,
                                              float* __restrict__ out1,
                                              float* __restrict__ out3) {
  const int i = blockIdx.x;
  const int ci = dpidx[i];
  const double thr = maxcos[i];
  const size_t rb = (size_t)i * B_N;
#pragma unroll 2
  for (int it = 0; it < 8; ++it) {
    int j = it * 1024 + threadIdx.x * 4;
    int4 c4 = *(const int4*)&dpidx[j];
    int m0 = (c4.x == ci) & ((j + 0) != i);
    int m1 = (c4.y == ci) & ((j + 1) != i);
    int m2 = (c4.z == ci) & ((j + 2) != i);
    int m3 = (c4.w == ci) & ((j + 3) != i);
    float4 bv = make_float4(0.f, 0.f, 0.f, 0.f);
    if (m0 | m1 | m2 | m3)                       // exec-masked sparse fetch
      bv = *(const float4*)&batch[rb + j];
    float4 cl = make_float4((float)m0, (float)m1, (float)m2, (float)m3);
    float4 mk = make_float4(
        (m0 && ((double)bv.x > thr)) ? -10000.f : 0.f,
        (m1 && ((double)bv.y > thr)) ? -10000.f : 0.f,
        (m2 && ((double)bv.z > thr)) ? -10000.f : 0.f,
        (m3 && ((double)bv.w > thr)) ? -10000.f : 0.f);
    *(float4*)&out1[rb + j] = cl;
    *(float4*)&out3[rb + j] = mk;
  }
}

// ---- deterministic per-(cluster, row-chunk) partial sums ----
__global__ __launch_bounds__(256) void cluster_partial_k(const float* __restrict__ dp,
                                                         const int* __restrict__ dpidx,
                                                         double* __restrict__ psum,
                                                         int* __restrict__ pcnt,
                                                         int nch) {
  const int k = blockIdx.x & 127;
  const int ch = blockIdx.x >> 7;
  const int rows = B_N / nch;
  const int r0 = ch * rows;
  const int t = threadIdx.x;
  double a0 = 0, a1 = 0, a2 = 0, a3 = 0;
  int cnt = 0;
  for (int r = r0; r < r0 + rows; r += 4) {
    int4 q = *(const int4*)&dpidx[r];
    if (q.x == k) { float4 v = *(const float4*)&dp[(size_t)(r + 0) * D_N + t * 4];
                    a0 += v.x; a1 += v.y; a2 += v.z; a3 += v.w; ++cnt; }
    if (q.y == k) { float4 v = *(const float4*)&dp[(size_t)(r + 1) * D_N + t * 4];
                    a0 += v.x; a1 += v.y; a2 += v.z; a3 += v.w; ++cnt; }
    if (q.z == k) { float4 v = *(const float4*)&dp[(size_t)(r + 2) * D_N + t * 4];
                    a0 += v.x; a1 += v.y; a2 += v.z; a3 += v.w; ++cnt; }
    if (q.w == k) { float4 v = *(const float4*)&dp[(size_t)(r + 3) * D_N + t * 4];
                    a0 += v.x; a1 += v.y; a2 += v.z; a3 += v.w; ++cnt; }
  }
  double* o = psum + ((size_t)(ch * 128 + k)) * D_N + t * 4;
  o[0] = a0; o[1] = a1; o[2] = a2; o[3] = a3;
  if (t == 0) pcnt[ch * 128 + k] = cnt;
}

// ---- new_centroid = cnt>0 ? 0.5*sum + 0.5*c : c ----
__global__ __launch_bounds__(256) void finalize_k(const float* __restrict__ cent,
                                                  const double* __restrict__ psum,
                                                  const int* __restrict__ pcnt,
                                                  float* __restrict__ out4,
                                                  int nch) {
  int e = blockIdx.x * 256 + threadIdx.x;   // < 131072
  int k = e >> 10;
  int cnt = 0;
  double s = 0.0;
  for (int ch = 0; ch < nch; ++ch) {
    cnt += pcnt[ch * 128 + k];
    s += psum[(size_t)(ch * 128 + k) * D_N + (e & 1023)];
  }
  float c = cent[e];
  out4[e] = (cnt > 0) ? (float)(0.5 * s + 0.5 * (double)c) : c;
}

extern "C" void kernel_launch(void* const* d_in, const int* in_sizes, int n_in,
                              void* d_out, int out_size, void* d_ws, size_t ws_size,
                              hipStream_t stream) {
  const float* dp    = (const float*)d_in[0];   // 8192 x 1024
  const float* cent  = (const float*)d_in[1];   // 128 x 1024
  const float* batch = (const float*)d_in[2];   // 8192 x 8192

  float* out  = (float*)d_out;
  float* out0 = out;                 // dp_centroid   8192x1024
  float* out1 = out0 + 8388608;      // dp_cluster    8192x8192
  float* out2 = out1 + 67108864;     // hard_negative 8192x1024
  float* out3 = out2 + 8388608;      // cos_mask      8192x8192
  float* out4 = out3 + 67108864;     // new_centroid  128x1024

  char* w = (char*)d_ws;
  double* xnorm2 = (double*)(w + 0);
  double* cnorm2 = (double*)(w + 65536);
  int*    dpidx  = (int*)(w + 66560);
  double* maxcos = (double*)(w + 99328);
  float*  ct     = (float*)(w + 164864);
  float*  pdot   = (float*)(w + 689152);        // 4*8192*128 f32 = 16 MB
  const size_t psum_base = 689152 + 16777216;   // 17466368

  int nch = 16;
  while (nch > 1 &&
         psum_base + (size_t)nch * (128ull * 1024 * 8 + 128 * 4) > ws_size)
    nch >>= 1;
  double* psum = (double*)(w + psum_base);
  int*    pcnt = (int*)(w + psum_base + (size_t)nch * 128 * 1024 * 8);

  transpose_cent_k<<<dim3(512), dim3(256), 0, stream>>>(cent, ct);
  norms_k<<<dim3(2048), dim3(256), 0, stream>>>(dp, xnorm2);
  norms_k<<<dim3(32), dim3(256), 0, stream>>>(cent, cnorm2);
  assign_part_k<<<dim3(1024), dim3(256), 0, stream>>>(dp, ct, pdot);
  top2_gather_k<<<dim3(2048), dim3(256), 0, stream>>>(pdot, xnorm2, cnorm2, cent,
                                                      dpidx, maxcos, out0, out2);
  mask_k<<<dim3(8192), dim3(256), 0, stream>>>(batch, dpidx, maxcos, out1, out3);
  cluster_partial_k<<<dim3(128 * nch), dim3(256), 0, stream>>>(dp, dpidx, psum, pcnt, nch);
  finalize_k<<<dim3(512), dim3(256), 0, stream>>>(cent, psum, pcnt, out4, nch);
}

// Round 5
// 247.562 us; speedup vs baseline: 1.3163x; 1.0574x over previous
//
#include <hip/hip_runtime.h>
#include <cmath>

#define B_N 8192
#define D_N 1024
#define K_N 128

typedef float float4v __attribute__((ext_vector_type(4)));

// ---------------- workspace layout (bytes) ----------------
// xnorm2  double[8192]      @ 0         (65536)
// cnorm2  double[128]       @ 65536     (1024)
// dpidx   int[8192]         @ 66560     (32768)
// maxcos  double[8192]      @ 99328     (65536)
// ct      float[1024*128]   @ 164864    (524288)   centroid transposed [d][k]
// pdot    float[4*8192*128] @ 689152    (16777216) split-D(4) f32 partial dots
// psum    double[nch*128*1024] @ 17466368
// pcnt    int[nch*128]      @ after psum

__device__ __forceinline__ void row_norm2(const float* __restrict__ src, int row,
                                          double* __restrict__ out) {
  int lane = threadIdx.x & 63;
  const float4* s4 = (const float4*)(src + (size_t)row * D_N);
  double acc = 0.0;
#pragma unroll
  for (int e = 0; e < 4; ++e) {
    float4 v = s4[e * 64 + lane];
    acc += (double)v.x * v.x + (double)v.y * v.y + (double)v.z * v.z + (double)v.w * v.w;
  }
#pragma unroll
  for (int off = 32; off; off >>= 1) acc += __shfl_xor(acc, off, 64);
  if (lane == 0) out[row] = acc;
}

// ---- hetero prep: transpose + dp norms + cent norms in one launch ----
// blocks [0,512): transpose; [512,2560): dp norms; [2560,2592): cent norms
__global__ __launch_bounds__(256) void prep_k(const float* __restrict__ dp,
                                              const float* __restrict__ cent,
                                              float* __restrict__ ct,
                                              double* __restrict__ xnorm2,
                                              double* __restrict__ cnorm2) {
  int bid = blockIdx.x;
  if (bid < 512) {
    int e = bid * 256 + threadIdx.x;          // < 131072
    int k = e >> 10, d = e & 1023;
    ct[d * K_N + k] = cent[e];
  } else if (bid < 2560) {
    int w = threadIdx.x >> 6;
    row_norm2(dp, (bid - 512) * 4 + w, xnorm2);
  } else {
    int w = threadIdx.x >> 6;
    row_norm2(cent, (bid - 2560) * 4 + w, cnorm2);
  }
}

// ---- stage 1: split-D(4) GEMM, R=8 register blocking, f32 partials ----
// grid 512: h = bid>>7 in {0..3}, rb = bid&127 -> rows rb*64..+64
// 48 KB LDS -> 3 blocks/CU; per-thread 8 rows x 4 cents.
__global__ __launch_bounds__(256, 3) void assign_part_k(const float* __restrict__ dp,
                                                        const float* __restrict__ ct,
                                                        float* __restrict__ pdot) {
  __shared__ __align__(16) float xs[64 * 64];      // [row][d]  16 KB
  __shared__ __align__(16) float cs[64 * K_N];     // [d][k]    32 KB
  const int tid = threadIdx.x;
  const int rg = tid >> 5;          // 0..7  -> rows rg*8..+8
  const int cg = tid & 31;          // 0..31 -> cents cg*4..+4
  const int h = blockIdx.x >> 7;
  const int rowbase = (blockIdx.x & 127) * 64;
  const int dbase = h * 256;

  float a32[8][4];
  double a64[8][4];
#pragma unroll
  for (int r = 0; r < 8; ++r)
#pragma unroll
    for (int q = 0; q < 4; ++q) a64[r][q] = 0.0;

  for (int ch = 0; ch < 4; ++ch) {
    const int db = dbase + ch * 64;
    // stage xs: 64 rows x 64 d = 1024 float4, 4/thread
#pragma unroll
    for (int i = 0; i < 4; ++i) {
      int fid = tid + i * 256;
      int r = fid >> 4, c4 = (fid & 15) * 4;
      *(float4*)&xs[r * 64 + c4] =
          *(const float4*)&dp[(size_t)(rowbase + r) * D_N + db + c4];
    }
    // stage cs: 64 d x 128 k = 2048 float4, 8/thread
#pragma unroll
    for (int i = 0; i < 8; ++i) {
      int fid = tid + i * 256;
      int dd = fid >> 5, kq = (fid & 31) * 4;
      *(float4*)&cs[dd * K_N + kq] =
          *(const float4*)&ct[(size_t)(db + dd) * K_N + kq];
    }
    __syncthreads();

#pragma unroll
    for (int r = 0; r < 8; ++r)
#pragma unroll
      for (int q = 0; q < 4; ++q) a32[r][q] = 0.0f;

    for (int dd = 0; dd < 64; dd += 4) {
      float4 cf[4];
#pragma unroll
      for (int e = 0; e < 4; ++e)
        cf[e] = *(const float4*)&cs[(dd + e) * K_N + cg * 4];
#pragma unroll
      for (int r = 0; r < 8; ++r) {
        float4 xv = *(const float4*)&xs[(rg * 8 + r) * 64 + dd];
        a32[r][0] += xv.x * cf[0].x + xv.y * cf[1].x + xv.z * cf[2].x + xv.w * cf[3].x;
        a32[r][1] += xv.x * cf[0].y + xv.y * cf[1].y + xv.z * cf[2].y + xv.w * cf[3].y;
        a32[r][2] += xv.x * cf[0].z + xv.y * cf[1].z + xv.z * cf[2].z + xv.w * cf[3].z;
        a32[r][3] += xv.x * cf[0].w + xv.y * cf[1].w + xv.z * cf[2].w + xv.w * cf[3].w;
      }
    }
#pragma unroll
    for (int r = 0; r < 8; ++r)
#pragma unroll
      for (int q = 0; q < 4; ++q) a64[r][q] += (double)a32[r][q];
    __syncthreads();
  }

  float* base = pdot + (size_t)h * B_N * K_N;
#pragma unroll
  for (int r = 0; r < 8; ++r) {
    int row = rowbase + rg * 8 + r;
    float4 v = make_float4((float)a64[r][0], (float)a64[r][1],
                           (float)a64[r][2], (float)a64[r][3]);
    *(float4*)(base + (size_t)row * K_N + cg * 4) = v;
  }
}

// ---- stage 2: per-row top-2 (f64, index-stable) + fused gather ----
__global__ __launch_bounds__(256) void top2_gather_k(const float* __restrict__ pdot,
                                                     const double* __restrict__ xnorm2,
                                                     const double* __restrict__ cnorm2,
                                                     const float* __restrict__ cent,
                                                     int* __restrict__ dpidx,
                                                     double* __restrict__ maxcos,
                                                     float* __restrict__ out0,
                                                     float* __restrict__ out2) {
  const int w = threadIdx.x >> 6, l = threadIdx.x & 63;
  const int row = blockIdx.x * 4 + w;
  double s0 = 0.0, s1 = 0.0;
#pragma unroll
  for (int h = 0; h < 4; ++h) {
    float2 p = *(const float2*)&pdot[(size_t)h * B_N * K_N + (size_t)row * K_N + 2 * l];
    s0 += (double)p.x; s1 += (double)p.y;
  }
  double xinv = 1.0 / fmax(sqrt(xnorm2[row]), 1e-8);
  double2 cn = *(const double2*)&cnorm2[2 * l];
  double c0 = s0 * xinv / fmax(sqrt(cn.x), 1e-8);
  double c1 = s1 * xinv / fmax(sqrt(cn.y), 1e-8);

  double v1, v2; int i1, i2;
  if (c0 >= c1) { v1 = c0; i1 = 2 * l;     v2 = c1; i2 = 2 * l + 1; }
  else          { v1 = c1; i1 = 2 * l + 1; v2 = c0; i2 = 2 * l; }

#pragma unroll
  for (int off = 1; off < 64; off <<= 1) {
    double pv1 = __shfl_xor(v1, off, 64), pv2 = __shfl_xor(v2, off, 64);
    int    pi1 = __shfl_xor(i1, off, 64), pi2 = __shfl_xor(i2, off, 64);
    bool pb = (pv1 > v1) || (pv1 == v1 && pi1 < i1);
    double w1v = pb ? pv1 : v1;  int w1i = pb ? pi1 : i1;
    double lv  = pb ? v1  : pv1; int li  = pb ? i1  : pi1;   // loser of firsts
    double sv  = pb ? pv2 : v2;  int si  = pb ? pi2 : i2;    // winner-side second
    bool lb = (lv > sv) || (lv == sv && li < si);
    v1 = w1v; i1 = w1i;
    v2 = lb ? lv : sv; i2 = lb ? li : si;
  }
  if (l == 0) { dpidx[row] = i1; maxcos[row] = v1; }

  const float4* g1 = (const float4*)(cent + (size_t)i1 * D_N);
  const float4* g2 = (const float4*)(cent + (size_t)i2 * D_N);
  float4* o0 = (float4*)(out0 + (size_t)row * D_N);
  float4* o2 = (float4*)(out2 + (size_t)row * D_N);
#pragma unroll
  for (int e = 0; e < 4; ++e) {
    o0[e * 64 + l] = g1[e * 64 + l];
    o2[e * 64 + l] = g2[e * 64 + l];
  }
}

// ---- hetero: cluster_partial blocks first, then mask blocks ----
// blocks [0, npart): per-(cluster, chunk) partial sums
// blocks [npart, npart+8192): dp_cluster + cos_mask row kernels
__global__ __launch_bounds__(256) void maskpart_k(const float* __restrict__ batch,
                                                  const float* __restrict__ dp,
                                                  const int* __restrict__ dpidx,
                                                  const double* __restrict__ maxcos,
                                                  float* __restrict__ out1,
                                                  float* __restrict__ out3,
                                                  double* __restrict__ psum,
                                                  int* __restrict__ pcnt,
                                                  int nch, int npart) {
  const int bid = blockIdx.x;
  const int t = threadIdx.x;
  if (bid < npart) {
    const int k = bid & 127;
    const int ch = bid >> 7;
    const int rows = B_N / nch;
    const int r0 = ch * rows;
    double a0 = 0, a1 = 0, a2 = 0, a3 = 0;
    int cnt = 0;
    for (int r = r0; r < r0 + rows; r += 4) {
      int4 q = *(const int4*)&dpidx[r];
      if (q.x == k) { float4 v = *(const float4*)&dp[(size_t)(r + 0) * D_N + t * 4];
                      a0 += v.x; a1 += v.y; a2 += v.z; a3 += v.w; ++cnt; }
      if (q.y == k) { float4 v = *(const float4*)&dp[(size_t)(r + 1) * D_N + t * 4];
                      a0 += v.x; a1 += v.y; a2 += v.z; a3 += v.w; ++cnt; }
      if (q.z == k) { float4 v = *(const float4*)&dp[(size_t)(r + 2) * D_N + t * 4];
                      a0 += v.x; a1 += v.y; a2 += v.z; a3 += v.w; ++cnt; }
      if (q.w == k) { float4 v = *(const float4*)&dp[(size_t)(r + 3) * D_N + t * 4];
                      a0 += v.x; a1 += v.y; a2 += v.z; a3 += v.w; ++cnt; }
    }
    double* o = psum + ((size_t)(ch * 128 + k)) * D_N + t * 4;
    o[0] = a0; o[1] = a1; o[2] = a2; o[3] = a3;
    if (t == 0) pcnt[ch * 128 + k] = cnt;
  } else {
    const int i = bid - npart;
    const int ci = dpidx[i];
    const double thr = maxcos[i];
    const size_t rb = (size_t)i * B_N;
#pragma unroll 2
    for (int it = 0; it < 8; ++it) {
      int j = it * 1024 + t * 4;
      int4 c4 = *(const int4*)&dpidx[j];
      int m0 = (c4.x == ci) & ((j + 0) != i);
      int m1 = (c4.y == ci) & ((j + 1) != i);
      int m2 = (c4.z == ci) & ((j + 2) != i);
      int m3 = (c4.w == ci) & ((j + 3) != i);
      float4v bv = (float4v){0.f, 0.f, 0.f, 0.f};
      if (m0 | m1 | m2 | m3)                       // exec-masked sparse fetch
        bv = __builtin_nontemporal_load((const float4v*)&batch[rb + j]);
      float4v cl = (float4v){(float)m0, (float)m1, (float)m2, (float)m3};
      float4v mk = (float4v){
          (m0 && ((double)bv.x > thr)) ? -10000.f : 0.f,
          (m1 && ((double)bv.y > thr)) ? -10000.f : 0.f,
          (m2 && ((double)bv.z > thr)) ? -10000.f : 0.f,
          (m3 && ((double)bv.w > thr)) ? -10000.f : 0.f};
      __builtin_nontemporal_store(cl, (float4v*)&out1[rb + j]);
      __builtin_nontemporal_store(mk, (float4v*)&out3[rb + j]);
    }
  }
}

// ---- new_centroid = cnt>0 ? 0.5*sum + 0.5*c : c ----
__global__ __launch_bounds__(256) void finalize_k(const float* __restrict__ cent,
                                                  const double* __restrict__ psum,
                                                  const int* __restrict__ pcnt,
                                                  float* __restrict__ out4,
                                                  int nch) {
  int e = blockIdx.x * 256 + threadIdx.x;   // < 131072
  int k = e >> 10;
  int cnt = 0;
  double s = 0.0;
  for (int ch = 0; ch < nch; ++ch) {
    cnt += pcnt[ch * 128 + k];
    s += psum[(size_t)(ch * 128 + k) * D_N + (e & 1023)];
  }
  float c = cent[e];
  out4[e] = (cnt > 0) ? (float)(0.5 * s + 0.5 * (double)c) : c;
}

extern "C" void kernel_launch(void* const* d_in, const int* in_sizes, int n_in,
                              void* d_out, int out_size, void* d_ws, size_t ws_size,
                              hipStream_t stream) {
  const float* dp    = (const float*)d_in[0];   // 8192 x 1024
  const float* cent  = (const float*)d_in[1];   // 128 x 1024
  const float* batch = (const float*)d_in[2];   // 8192 x 8192

  float* out  = (float*)d_out;
  float* out0 = out;                 // dp_centroid   8192x1024
  float* out1 = out0 + 8388608;      // dp_cluster    8192x8192
  float* out2 = out1 + 67108864;     // hard_negative 8192x1024
  float* out3 = out2 + 8388608;      // cos_mask      8192x8192
  float* out4 = out3 + 67108864;     // new_centroid  128x1024

  char* w = (char*)d_ws;
  double* xnorm2 = (double*)(w + 0);
  double* cnorm2 = (double*)(w + 65536);
  int*    dpidx  = (int*)(w + 66560);
  double* maxcos = (double*)(w + 99328);
  float*  ct     = (float*)(w + 164864);
  float*  pdot   = (float*)(w + 689152);        // 4*8192*128 f32 = 16 MB
  const size_t psum_base = 689152 + 16777216;   // 17466368

  int nch = 16;
  while (nch > 1 &&
         psum_base + (size_t)nch * (128ull * 1024 * 8 + 128 * 4) > ws_size)
    nch >>= 1;
  double* psum = (double*)(w + psum_base);
  int*    pcnt = (int*)(w + psum_base + (size_t)nch * 128 * 1024 * 8);
  const int npart = 128 * nch;

  prep_k<<<dim3(2592), dim3(256), 0, stream>>>(dp, cent, ct, xnorm2, cnorm2);
  assign_part_k<<<dim3(512), dim3(256), 0, stream>>>(dp, ct, pdot);
  top2_gather_k<<<dim3(2048), dim3(256), 0, stream>>>(pdot, xnorm2, cnorm2, cent,
                                                      dpidx, maxcos, out0, out2);
  maskpart_k<<<dim3(npart + 8192), dim3(256), 0, stream>>>(batch, dp, dpidx, maxcos,
                                                           out1, out3, psum, pcnt,
                                                           nch, npart);
  finalize_k<<<dim3(512), dim3(256), 0, stream>>>(cent, psum, pcnt, out4, nch);
}